// Round 12
// baseline (89.146 us; speedup 1.0000x reference)
//
#include <hip/hip_runtime.h>
#include <hip/hip_bf16.h>
#include <math.h>

// Problem constants
#define B_ 512
#define L_ 256
#define D_ 256
#define V_ 100000
#define O_ 1000

typedef __attribute__((ext_vector_type(8))) short short8;
typedef __attribute__((ext_vector_type(4))) float f32x4;

static __device__ __forceinline__ unsigned short f2bf(float f) {
    union { float f; unsigned u; } v; v.f = f;
    unsigned r = v.u + 0x7FFFu + ((v.u >> 16) & 1u);   // RNE (inputs are finite)
    return (unsigned short)(r >> 16);
}
static __device__ __forceinline__ float bf2f(unsigned short u) {
    union { unsigned u; float f; } v; v.u = ((unsigned)u) << 16;
    return v.f;
}
static __device__ __forceinline__ short8 pack8(float4 a, float4 c) {
    short8 o;
    o[0] = (short)f2bf(a.x); o[1] = (short)f2bf(a.y);
    o[2] = (short)f2bf(a.z); o[3] = (short)f2bf(a.w);
    o[4] = (short)f2bf(c.x); o[5] = (short)f2bf(c.y);
    o[6] = (short)f2bf(c.z); o[7] = (short)f2bf(c.w);
    return o;
}
// fred bank-spread swizzle (valid as fsw(base)+j, j<4, base%4==0)
static __device__ __forceinline__ int fsw(int d) { return d ^ (((d >> 5) & 7) << 2); }

// ---------------- Kernel 1: W_b cast to bf16 (row-major) ----------------
__global__ __launch_bounds__(256) void k_wt(const float* __restrict__ Wb,
                                            unsigned short* __restrict__ Wbf) {
    int i = blockIdx.x * 256 + threadIdx.x;       // 65536
    Wbf[i] = f2bf(Wb[i]);
}

// ---------------- Kernel 2 (fused): per-batch gather + G = E_b*W_b*E_b^T + softmax + f_w ----
// One block per batch, 1024 threads (16 waves = 4 waves/SIMD), 1 block/CU (160KB LDS).
// Round-12 change vs r11: SAME strip pipeline, but 16 waves x 16 rows/wave so the
// register tiling (wfr[8]+efr[8] = 64 VGPR) fits __launch_bounds__(1024,4)'s 128-VGPR
// cap -> 2x the waves/SIMD of r6/r9/r11 (which plateaued at 66-70us, occ 21%).
//   Step s (1..7) fuses P1(s) (H' strip -> Ht[s&1]) with P2(s-1) (G strip -> rowmax)
//   in one k-loop: two independent MFMA+LDS streams per wave.
// Es swizzle: row r, 16B-chunk c at r*512 + (c*16 ^ ((r&7)<<4)). One barrier per step.
// tanh(max)=max(tanh) -> softmax over L -> f_w = a^T E (from Es; fred bank-swizzled).
__global__ __launch_bounds__(1024, 4) void k_attn(const int* __restrict__ tok,
                                                  const float* __restrict__ emb,
                                                  const unsigned short* __restrict__ Wbf,
                                                  float* __restrict__ fw) {
    __shared__ __align__(16) char lds[163840];
    char* EsC = lds;                                   // 128KB: swizzled E_b
    float* red2    = (float*)(lds + 131072);           // overlay: 256 f32 (on Ht0, post-loop)
    float* scratch = (float*)(lds + 132096);           // overlay: 16 f32
    float* fred    = (float*)(lds + 132160);           // overlay: 16 x 256 f32

    int b = blockIdx.x;
    int tid = threadIdx.x;
    int wid = tid >> 6, ln = tid & 63;
    int l16 = ln & 15, gp = ln >> 4;
    int i0 = wid * 16;          // wave's Wb-row block (P1) / G-row block (P2)
    const int* tb = tok + (b << 8);

    // ---- Wb A-frag preload (global, L2-hot): rows [i0, i0+16) -> 32 VGPR ----
    short8 wfr[8];
#pragma unroll
    for (int k = 0; k < 8; k++)
        wfr[k] = *(const short8*)(Wbf + ((i0 + l16) << 8) + k * 32 + gp * 8);

    // ---- gather rows 0..63 (2 its of 1024 chunks) ----
#pragma unroll
    for (int it = 0; it < 2; it++) {
        int c = it * 1024 + tid;
        int row = c >> 5, c16 = c & 31;
        const float4* src = (const float4*)(emb + ((size_t)tb[row] << 8) + (c16 << 3));
        short8 o = pack8(src[0], src[1]);
        *(short8*)(EsC + ((row << 9) | ((c16 << 4) ^ ((row & 7) << 4)))) = o;
    }
    __syncthreads();   // barrier A: rows 0-63 visible

    // ---- issue loads for rows 64..159 into regs; land after P1(0) ----
    float4 ga[3], gb[3];
#pragma unroll
    for (int it = 0; it < 3; it++) {
        int c = (it + 2) * 1024 + tid;
        int row = c >> 5, c16 = c & 31;
        const float4* src = (const float4*)(emb + ((size_t)tb[row] << 8) + (c16 << 3));
        ga[it] = src[0]; gb[it] = src[1];
    }

    float rmax[4];
#pragma unroll
    for (int i = 0; i < 4; i++) rmax[i] = -1e30f;

    // ---- P1-only strip (step 0) ----
    auto P1strip = [&](int s, char* HtW) {
        f32x4 acc[2] = {};
#pragma unroll
        for (int k0 = 0; k0 < 256; k0 += 32) {
            int kk2 = (k0 + gp * 8) * 2;
            short8 b1[2];
#pragma unroll
            for (int cf = 0; cf < 2; cf++) {
                int jg = s * 32 + cf * 16 + l16;
                b1[cf] = *(const short8*)(EsC + ((jg << 9) | (kk2 ^ ((jg & 7) << 4))));
            }
            int ks = k0 >> 5;
            __builtin_amdgcn_s_setprio(1);
#pragma unroll
            for (int cf = 0; cf < 2; cf++)
                acc[cf] = __builtin_amdgcn_mfma_f32_16x16x32_bf16(
                    wfr[ks], b1[cf], acc[cf], 0, 0, 0);
            __builtin_amdgcn_s_setprio(0);
        }
#pragma unroll
        for (int cf = 0; cf < 2; cf++) {
            int i = i0 + gp * 4;
            int jl = cf * 16 + l16;
            unsigned long long pk;
            unsigned short* p = (unsigned short*)&pk;
            p[0] = f2bf(acc[cf][0]);
            p[1] = f2bf(acc[cf][1]);
            p[2] = f2bf(acc[cf][2]);
            p[3] = f2bf(acc[cf][3]);
            *(unsigned long long*)(HtW + ((jl << 9) | ((i * 2) ^ ((jl & 7) << 4)))) = pk;
        }
    };

    short8 efr[8];
    // ---- P2-only strip (step 8 epilogue) ----
    auto P2strip = [&](char* HtR) {
        f32x4 acc[2] = {};
#pragma unroll
        for (int k0 = 0; k0 < 256; k0 += 32) {
            int kk2 = (k0 + gp * 8) * 2;
            short8 b2[2];
#pragma unroll
            for (int cf = 0; cf < 2; cf++) {
                int m = cf * 16 + l16;
                b2[cf] = *(const short8*)(HtR + ((m << 9) | (kk2 ^ ((m & 7) << 4))));
            }
            int ks = k0 >> 5;
            __builtin_amdgcn_s_setprio(1);
#pragma unroll
            for (int cf = 0; cf < 2; cf++)
                acc[cf] = __builtin_amdgcn_mfma_f32_16x16x32_bf16(
                    efr[ks], b2[cf], acc[cf], 0, 0, 0);
            __builtin_amdgcn_s_setprio(0);
        }
#pragma unroll
        for (int r = 0; r < 4; r++)
            rmax[r] = fmaxf(rmax[r], fmaxf(acc[0][r], acc[1][r]));
    };

    // ---- step 0: P1(0) -> Ht0, with gather overlap ----
    P1strip(0, lds + 131072);

    // land rows 64..159 (P1(0) read only rows 0-31; disjoint)
#pragma unroll
    for (int it = 0; it < 3; it++) {
        int c = (it + 2) * 1024 + tid;
        int row = c >> 5, c16 = c & 31;
        short8 o = pack8(ga[it], gb[it]);
        *(short8*)(EsC + ((row << 9) | ((c16 << 4) ^ ((row & 7) << 4)))) = o;
    }
    // gather rows 160..255 (its 5..7)
#pragma unroll
    for (int it = 5; it < 8; it++) {
        int c = it * 1024 + tid;
        int row = c >> 5, c16 = c & 31;
        const float4* src = (const float4*)(emb + ((size_t)tb[row] << 8) + (c16 << 3));
        short8 o = pack8(src[0], src[1]);
        *(short8*)(EsC + ((row << 9) | ((c16 << 4) ^ ((row & 7) << 4)))) = o;
    }
    __syncthreads();   // barrier B: all E rows + Ht0 visible

    // ---- E A-frag preload (from LDS): rows [i0, i0+16) -> 32 VGPR ----
#pragma unroll
    for (int k = 0; k < 8; k++) {
        int l = i0 + l16;
        efr[k] = *(const short8*)(EsC + ((l << 9) | ((k * 64 + gp * 16) ^ ((l & 7) << 4))));
    }

    // ---- steps 1..7: fused P1(s) || P2(s-1), one barrier per step ----
    for (int s = 1; s < 8; s++) {
        char* HtW = lds + 131072 + ((s & 1) << 14);
        char* HtR = lds + 131072 + (((s - 1) & 1) << 14);
        f32x4 a1[2] = {};
        f32x4 a2[2] = {};
#pragma unroll
        for (int k0 = 0; k0 < 256; k0 += 32) {
            int kk2 = (k0 + gp * 8) * 2;
            short8 b1[2], b2[2];
#pragma unroll
            for (int cf = 0; cf < 2; cf++) {
                int jg = s * 32 + cf * 16 + l16;
                b1[cf] = *(const short8*)(EsC + ((jg << 9) | (kk2 ^ ((jg & 7) << 4))));
                int m = cf * 16 + l16;
                b2[cf] = *(const short8*)(HtR + ((m << 9) | (kk2 ^ ((m & 7) << 4))));
            }
            int ks = k0 >> 5;
            __builtin_amdgcn_s_setprio(1);
#pragma unroll
            for (int cf = 0; cf < 2; cf++) {
                a1[cf] = __builtin_amdgcn_mfma_f32_16x16x32_bf16(
                    wfr[ks], b1[cf], a1[cf], 0, 0, 0);
                a2[cf] = __builtin_amdgcn_mfma_f32_16x16x32_bf16(
                    efr[ks], b2[cf], a2[cf], 0, 0, 0);
            }
            __builtin_amdgcn_s_setprio(0);
        }
        // store Ht strip s
#pragma unroll
        for (int cf = 0; cf < 2; cf++) {
            int i = i0 + gp * 4;
            int jl = cf * 16 + l16;
            unsigned long long pk;
            unsigned short* p = (unsigned short*)&pk;
            p[0] = f2bf(a1[cf][0]);
            p[1] = f2bf(a1[cf][1]);
            p[2] = f2bf(a1[cf][2]);
            p[3] = f2bf(a1[cf][3]);
            *(unsigned long long*)(HtW + ((jl << 9) | ((i * 2) ^ ((jl & 7) << 4)))) = pk;
        }
        // rowmax from P2(s-1)
#pragma unroll
        for (int r = 0; r < 4; r++)
            rmax[r] = fmaxf(rmax[r], fmaxf(a2[0][r], a2[1][r]));
        __syncthreads();
    }

    // ---- step 8: P2(7) from Ht1 ----
    P2strip(lds + 131072 + (1 << 14));

    // ---- reduce rowmax across l16 lanes, publish to red2 ----
#pragma unroll
    for (int i = 0; i < 4; i++) {
        float v = rmax[i];
        v = fmaxf(v, __shfl_xor(v, 1));
        v = fmaxf(v, __shfl_xor(v, 2));
        v = fmaxf(v, __shfl_xor(v, 4));
        v = fmaxf(v, __shfl_xor(v, 8));
        rmax[i] = v;
    }
    __syncthreads();   // Ht0 dead; red2 overlay safe
    if (l16 == 0) {
#pragma unroll
        for (int r = 0; r < 4; r++)
            red2[i0 + gp * 4 + r] = rmax[r];
    }
    __syncthreads();

    // ---- tanh + softmax over the 256 row-maxima (waves 0-3 carry data) ----
    float x = -1e30f;
    if (tid < 256) x = tanhf(red2[tid]);
    float mx = x;
#pragma unroll
    for (int s = 1; s < 64; s <<= 1) mx = fmaxf(mx, __shfl_xor(mx, s));
    if (ln == 0 && wid < 4) scratch[wid] = mx;
    __syncthreads();
    float bm = fmaxf(fmaxf(scratch[0], scratch[1]), fmaxf(scratch[2], scratch[3]));
    float e = (tid < 256) ? expf(x - bm) : 0.f;
    float sm = e;
#pragma unroll
    for (int s = 1; s < 64; s <<= 1) sm += __shfl_xor(sm, s);
    if (ln == 0 && wid < 4) scratch[8 + wid] = sm;
    __syncthreads();
    float tot = (scratch[8] + scratch[9]) + (scratch[10] + scratch[11]);
    if (tid < 256) red2[tid] = e / tot;    // aq
    __syncthreads();

    // ---- f_w[d] = sum_l aq[l] * E_b[l][d]  (threads 0-511; fred bank-swizzled) ----
    if (tid < 512) {
        int g = tid >> 5;                    // 0..15 -> l-range [16g, 16g+16)
        int d0 = (tid & 31) << 3;            // 8 d's per thread
        float s0[8] = {0.f, 0.f, 0.f, 0.f, 0.f, 0.f, 0.f, 0.f};
        int lbase = g << 4;
#pragma unroll
        for (int li = 0; li < 16; li++) {
            int l = lbase + li;
            float aql = red2[l];
            int byt = (l << 9) | ((d0 * 2) ^ ((l & 7) << 4));
            short8 v = *(const short8*)(EsC + byt);
#pragma unroll
            for (int jj = 0; jj < 8; jj++)
                s0[jj] += aql * bf2f((unsigned short)v[jj]);
        }
        f32x4 w0, w1;
        w0[0] = s0[0]; w0[1] = s0[1]; w0[2] = s0[2]; w0[3] = s0[3];
        w1[0] = s0[4]; w1[1] = s0[5]; w1[2] = s0[6]; w1[3] = s0[7];
        *(f32x4*)(fred + g * 256 + fsw(d0)) = w0;
        *(f32x4*)(fred + g * 256 + fsw(d0 + 4)) = w1;
    }
    __syncthreads();
    if (tid < 256) {
        float f = 0.f;
        int dw = fsw(tid);
#pragma unroll
        for (int g2 = 0; g2 < 16; g2++) f += fred[g2 * 256 + dw];
        fw[(b << 8) + tid] = f;
    }
}

// ---------------- Kernel 3: out = f_w @ lin_w^T + lin_b  (fp32 tiled GEMM) ----------------
// Tile 32(M)x64(N), 256 blocks (full CU coverage), float4 staging.
__global__ __launch_bounds__(256) void k_out(const float* __restrict__ fw,
                                             const float* __restrict__ lw,
                                             const float* __restrict__ lb,
                                             float* __restrict__ out) {
    __shared__ float As[32][68];
    __shared__ float Bs[64][65];
    int tid = threadIdx.x;
    int tx = tid & 15, ty = tid >> 4;
    int r0 = blockIdx.y * 32, n0 = blockIdx.x * 64;
    float acc[2][4] = {};
    for (int k0 = 0; k0 < 256; k0 += 64) {
        __syncthreads();
#pragma unroll
        for (int it = 0; it < 2; it++) {
            int idx = it * 256 + tid;
            int i = idx >> 4, k4 = (idx & 15) << 2;
            *(float4*)&As[i][k4] = *(const float4*)&fw[(r0 + i) * 256 + k0 + k4];
        }
#pragma unroll
        for (int it = 0; it < 4; it++) {
            int idx = it * 256 + tid;
            int n = idx >> 4, k4 = (idx & 15) << 2;
            int nn = n0 + n;
            float4 v = {0.f, 0.f, 0.f, 0.f};
            if (nn < O_) v = *(const float4*)&lw[(size_t)nn * 256 + k0 + k4];
            Bs[k4][n] = v.x; Bs[k4 + 1][n] = v.y; Bs[k4 + 2][n] = v.z; Bs[k4 + 3][n] = v.w;
        }
        __syncthreads();
#pragma unroll
        for (int k = 0; k < 64; k++) {
            float a0 = As[ty * 2][k], a1 = As[ty * 2 + 1][k];
            float b0 = Bs[k][tx * 4], b1 = Bs[k][tx * 4 + 1];
            float b2 = Bs[k][tx * 4 + 2], b3 = Bs[k][tx * 4 + 3];
            acc[0][0] += a0 * b0; acc[0][1] += a0 * b1; acc[0][2] += a0 * b2; acc[0][3] += a0 * b3;
            acc[1][0] += a1 * b0; acc[1][1] += a1 * b1; acc[1][2] += a1 * b2; acc[1][3] += a1 * b3;
        }
    }
#pragma unroll
    for (int i = 0; i < 2; i++)
#pragma unroll
        for (int j = 0; j < 4; j++) {
            int n = n0 + tx * 4 + j;
            if (n < O_) out[(size_t)(r0 + ty * 2 + i) * O_ + n] = acc[i][j] + lb[n];
        }
}

extern "C" void kernel_launch(void* const* d_in, const int* in_sizes, int n_in,
                              void* d_out, int out_size, void* d_ws, size_t ws_size,
                              hipStream_t stream) {
    const int* tok = (const int*)d_in[0];
    const float* emb = (const float*)d_in[1];
    const float* Wb = (const float*)d_in[2];
    const float* lw = (const float*)d_in[3];
    const float* lb = (const float*)d_in[4];
    float* out = (float*)d_out;

    char* ws = (char*)d_ws;
    unsigned short* Wbf = (unsigned short*)(ws);            // 131,072 B
    float*          fwp = (float*)(ws + 131072);            // 524,288 B

    hipLaunchKernelGGL(k_wt,   dim3(256),    dim3(256),  0, stream, Wb, Wbf);
    hipLaunchKernelGGL(k_attn, dim3(512),    dim3(1024), 0, stream, tok, emb, Wbf, fwp);
    hipLaunchKernelGGL(k_out,  dim3(16, 16), dim3(256),  0, stream, fwp, lw, lb, out);
}

// Round 13
// 81.263 us; speedup vs baseline: 1.0970x; 1.0970x over previous
//
#include <hip/hip_runtime.h>
#include <hip/hip_bf16.h>
#include <math.h>

// Problem constants
#define B_ 512
#define L_ 256
#define D_ 256
#define V_ 100000
#define O_ 1000

typedef __attribute__((ext_vector_type(8))) short short8;
typedef __attribute__((ext_vector_type(4))) float f32x4;

static __device__ __forceinline__ unsigned short f2bf(float f) {
    union { float f; unsigned u; } v; v.f = f;
    unsigned r = v.u + 0x7FFFu + ((v.u >> 16) & 1u);   // RNE (inputs are finite)
    return (unsigned short)(r >> 16);
}
static __device__ __forceinline__ float bf2f(unsigned short u) {
    union { unsigned u; float f; } v; v.u = ((unsigned)u) << 16;
    return v.f;
}
static __device__ __forceinline__ short8 pack8(float4 a, float4 c) {
    short8 o;
    o[0] = (short)f2bf(a.x); o[1] = (short)f2bf(a.y);
    o[2] = (short)f2bf(a.z); o[3] = (short)f2bf(a.w);
    o[4] = (short)f2bf(c.x); o[5] = (short)f2bf(c.y);
    o[6] = (short)f2bf(c.z); o[7] = (short)f2bf(c.w);
    return o;
}
// fred bank-spread swizzle (valid as fsw(base)+j, j<4, base%4==0)
static __device__ __forceinline__ int fsw(int d) { return d ^ (((d >> 5) & 7) << 2); }

// ---------------- Kernel 1: W_b cast to bf16 (row-major) ----------------
__global__ __launch_bounds__(256) void k_wt(const float* __restrict__ Wb,
                                            unsigned short* __restrict__ Wbf) {
    int i = blockIdx.x * 256 + threadIdx.x;       // 65536
    Wbf[i] = f2bf(Wb[i]);
}

// ---------------- Kernel 2 (fused): per-batch gather + G = E_b*W_b*E_b^T + softmax + f_w ----
// One block per batch, 1024 threads (16 waves = 4 waves/SIMD), 1 block/CU (160KB LDS).
// PRODUCER/CONSUMER SPLIT with 32-row wave tiles (r12 lesson: 16-row tiles double LDS
// reads; r10 lesson: keep operand arrays at 64 VGPR and gather unroll shallow):
//   waves 0-7  (producers): 32 Wb rows each in wfr[8][2] (64 VGPR). Step s: P1(s)
//     computes H'[own 32 rows][strip s (32 cols)] -> Ht[s&1] (16KB, transposed+swizzled).
//   waves 8-15 (consumers): 32 G rows each in efr[8][2] (64 VGPR, from Es at step 1).
//     Step s(>=1): P2(s-1) computes G[own rows][strip s-1] from Ht[(s-1)&1]; rowmax.
//     Step 0: consumers gather E rows 64-255 (unroll 2) under producers' P1(0).
//   One barrier per step. Each SIMD hosts 2 producer + 2 consumer waves -> independent
//   MFMA+LDS streams at different phases (role diversity; setprio arbitrates).
// Es swizzle: row r, 16B-chunk c at r*512 + (c*16 ^ ((r&7)<<4)).
// tanh(max)=max(tanh) -> softmax over L -> f_w = a^T E (from Es; fred bank-swizzled).
__global__ __launch_bounds__(1024, 4) void k_attn(const int* __restrict__ tok,
                                                  const float* __restrict__ emb,
                                                  const unsigned short* __restrict__ Wbf,
                                                  float* __restrict__ fw) {
    __shared__ __align__(16) char lds[163840];
    char* EsC = lds;                                   // 128KB: swizzled E_b
    float* red2    = (float*)(lds + 131072);           // overlay on Ht0 (post-loop): 256 f32
    float* scratch = (float*)(lds + 132096);           // overlay: 16 f32
    float* fred    = (float*)(lds + 132160);           // overlay: 16 x 256 f32

    int b = blockIdx.x;
    int tid = threadIdx.x;
    int wid = tid >> 6, ln = tid & 63;
    int l16 = ln & 15, gp = ln >> 4;
    bool prod = (wid < 8);
    int i0 = (prod ? wid : (wid - 8)) * 32;   // producer: Wb-row block; consumer: G-row block
    const int* tb = tok + (b << 8);

    // ---- all threads: gather rows 0..63 (2048 chunks / 1024 thr = 2 its) ----
#pragma unroll
    for (int it = 0; it < 2; it++) {
        int c = it * 1024 + tid;
        int row = c >> 5, c16 = c & 31;
        const float4* src = (const float4*)(emb + ((size_t)tb[row] << 8) + (c16 << 3));
        short8 o = pack8(src[0], src[1]);
        *(short8*)(EsC + ((row << 9) | ((c16 << 4) ^ ((row & 7) << 4)))) = o;
    }

    // ---- producers: Wb A-frag preload (global, L2-hot): rows [i0, i0+32) -> 64 VGPR ----
    short8 afr[8][2];     // producers: wfr; consumers: efr (loaded after step 0)
    if (prod) {
#pragma unroll
        for (int k = 0; k < 8; k++)
#pragma unroll
            for (int rf = 0; rf < 2; rf++)
                afr[k][rf] = *(const short8*)(Wbf + ((i0 + rf * 16 + l16) << 8) + k * 32 + gp * 8);
    }
    __syncthreads();   // barrier A: rows 0-63 visible

    float rmax[8];
#pragma unroll
    for (int i = 0; i < 8; i++) rmax[i] = -1e30f;

    // ---- P1 strip body (producers) ----
    auto P1strip = [&](int s, char* HtW) {
        f32x4 acc[2][2] = {};
#pragma unroll
        for (int k0 = 0; k0 < 256; k0 += 32) {
            int kk2 = (k0 + gp * 8) * 2;
            short8 b1[2];
#pragma unroll
            for (int cf = 0; cf < 2; cf++) {
                int jg = s * 32 + cf * 16 + l16;
                b1[cf] = *(const short8*)(EsC + ((jg << 9) | (kk2 ^ ((jg & 7) << 4))));
            }
            int ks = k0 >> 5;
            __builtin_amdgcn_s_setprio(1);
#pragma unroll
            for (int rf = 0; rf < 2; rf++)
#pragma unroll
                for (int cf = 0; cf < 2; cf++)
                    acc[rf][cf] = __builtin_amdgcn_mfma_f32_16x16x32_bf16(
                        afr[ks][rf], b1[cf], acc[rf][cf], 0, 0, 0);
            __builtin_amdgcn_s_setprio(0);
        }
        // store transposed: H'[i][j] -> Ht[j-local][i], 8B packs, swizzled
#pragma unroll
        for (int rf = 0; rf < 2; rf++)
#pragma unroll
            for (int cf = 0; cf < 2; cf++) {
                int i = i0 + rf * 16 + gp * 4;
                int jl = cf * 16 + l16;
                unsigned long long pk;
                unsigned short* p = (unsigned short*)&pk;
                p[0] = f2bf(acc[rf][cf][0]);
                p[1] = f2bf(acc[rf][cf][1]);
                p[2] = f2bf(acc[rf][cf][2]);
                p[3] = f2bf(acc[rf][cf][3]);
                *(unsigned long long*)(HtW + ((jl << 9) | ((i * 2) ^ ((jl & 7) << 4)))) = pk;
            }
    };

    // ---- P2 strip body (consumers) ----
    auto P2strip = [&](char* HtR) {
        f32x4 acc[2][2] = {};
#pragma unroll
        for (int k0 = 0; k0 < 256; k0 += 32) {
            int kk2 = (k0 + gp * 8) * 2;
            short8 b2[2];
#pragma unroll
            for (int cf = 0; cf < 2; cf++) {
                int m = cf * 16 + l16;
                b2[cf] = *(const short8*)(HtR + ((m << 9) | (kk2 ^ ((m & 7) << 4))));
            }
            int ks = k0 >> 5;
            __builtin_amdgcn_s_setprio(1);
#pragma unroll
            for (int rf = 0; rf < 2; rf++)
#pragma unroll
                for (int cf = 0; cf < 2; cf++)
                    acc[rf][cf] = __builtin_amdgcn_mfma_f32_16x16x32_bf16(
                        afr[ks][rf], b2[cf], acc[rf][cf], 0, 0, 0);
            __builtin_amdgcn_s_setprio(0);
        }
#pragma unroll
        for (int rf = 0; rf < 2; rf++)
#pragma unroll
            for (int r = 0; r < 4; r++)
                rmax[rf * 4 + r] = fmaxf(rmax[rf * 4 + r],
                                         fmaxf(acc[rf][0][r], acc[rf][1][r]));
    };

    // ---- step 0: producers P1(0) -> Ht0 ; consumers gather rows 64..255 ----
    if (prod) {
        P1strip(0, lds + 131072);
    } else {
        int t4 = tid - 512;    // 0..511
#pragma unroll 2
        for (int it = 0; it < 12; it++) {
            int c = it * 512 + t4;
            int row = 64 + (c >> 5), c16 = c & 31;
            const float4* src = (const float4*)(emb + ((size_t)tb[row] << 8) + (c16 << 3));
            short8 o = pack8(src[0], src[1]);
            *(short8*)(EsC + ((row << 9) | ((c16 << 4) ^ ((row & 7) << 4)))) = o;
        }
    }
    __syncthreads();   // barrier: all E rows + Ht0 visible

    // ---- consumers: E A-frag preload (from LDS): rows [i0, i0+32) -> 64 VGPR ----
    if (!prod) {
#pragma unroll
        for (int k = 0; k < 8; k++)
#pragma unroll
            for (int rf = 0; rf < 2; rf++) {
                int l = i0 + rf * 16 + l16;
                afr[k][rf] = *(const short8*)(EsC +
                    ((l << 9) | ((k * 64 + gp * 16) ^ ((l & 7) << 4))));
            }
    }

    // ---- steps 1..7: producers P1(s) -> Ht[s&1] ; consumers P2(s-1) <- Ht[(s-1)&1] ----
    for (int s = 1; s < 8; s++) {
        if (prod) P1strip(s, lds + 131072 + ((s & 1) << 14));
        else      P2strip(lds + 131072 + (((s - 1) & 1) << 14));
        __syncthreads();
    }
    // ---- step 8: consumers P2(7) <- Ht1 ----
    if (!prod) {
        P2strip(lds + 131072 + (1 << 14));
        // reduce rowmax across l16 lanes (Ht0 dead since step-7 barrier; red2 overlay safe)
#pragma unroll
        for (int i = 0; i < 8; i++) {
            float v = rmax[i];
            v = fmaxf(v, __shfl_xor(v, 1));
            v = fmaxf(v, __shfl_xor(v, 2));
            v = fmaxf(v, __shfl_xor(v, 4));
            v = fmaxf(v, __shfl_xor(v, 8));
            rmax[i] = v;
        }
        if (l16 == 0) {
#pragma unroll
            for (int rf = 0; rf < 2; rf++)
#pragma unroll
                for (int r = 0; r < 4; r++)
                    red2[i0 + rf * 16 + gp * 4 + r] = rmax[rf * 4 + r];
        }
    }
    __syncthreads();

    // ---- tanh + softmax over the 256 row-maxima (waves 0-3 carry data) ----
    float x = -1e30f;
    if (tid < 256) x = tanhf(red2[tid]);
    float mx = x;
#pragma unroll
    for (int s = 1; s < 64; s <<= 1) mx = fmaxf(mx, __shfl_xor(mx, s));
    if (ln == 0 && wid < 4) scratch[wid] = mx;
    __syncthreads();
    float bm = fmaxf(fmaxf(scratch[0], scratch[1]), fmaxf(scratch[2], scratch[3]));
    float e = (tid < 256) ? expf(x - bm) : 0.f;
    float sm = e;
#pragma unroll
    for (int s = 1; s < 64; s <<= 1) sm += __shfl_xor(sm, s);
    if (ln == 0 && wid < 4) scratch[8 + wid] = sm;
    __syncthreads();
    float tot = (scratch[8] + scratch[9]) + (scratch[10] + scratch[11]);
    if (tid < 256) red2[tid] = e / tot;    // aq
    __syncthreads();

    // ---- f_w[d] = sum_l aq[l] * E_b[l][d]  (threads 0-511; fred bank-swizzled) ----
    if (tid < 512) {
        int g = tid >> 5;                    // 0..15 -> l-range [16g, 16g+16)
        int d0 = (tid & 31) << 3;            // 8 d's per thread
        float s0[8] = {0.f, 0.f, 0.f, 0.f, 0.f, 0.f, 0.f, 0.f};
        int lbase = g << 4;
#pragma unroll
        for (int li = 0; li < 16; li++) {
            int l = lbase + li;
            float aql = red2[l];
            int byt = (l << 9) | ((d0 * 2) ^ ((l & 7) << 4));
            short8 v = *(const short8*)(EsC + byt);
#pragma unroll
            for (int jj = 0; jj < 8; jj++)
                s0[jj] += aql * bf2f((unsigned short)v[jj]);
        }
        f32x4 w0, w1;
        w0[0] = s0[0]; w0[1] = s0[1]; w0[2] = s0[2]; w0[3] = s0[3];
        w1[0] = s0[4]; w1[1] = s0[5]; w1[2] = s0[6]; w1[3] = s0[7];
        *(f32x4*)(fred + g * 256 + fsw(d0)) = w0;
        *(f32x4*)(fred + g * 256 + fsw(d0 + 4)) = w1;
    }
    __syncthreads();
    if (tid < 256) {
        float f = 0.f;
        int dw = fsw(tid);
#pragma unroll
        for (int g2 = 0; g2 < 16; g2++) f += fred[g2 * 256 + dw];
        fw[(b << 8) + tid] = f;
    }
}

// ---------------- Kernel 3: out = f_w @ lin_w^T + lin_b  (fp32 tiled GEMM) ----------------
// Tile 32(M)x64(N), 256 blocks (full CU coverage), float4 staging.
__global__ __launch_bounds__(256) void k_out(const float* __restrict__ fw,
                                             const float* __restrict__ lw,
                                             const float* __restrict__ lb,
                                             float* __restrict__ out) {
    __shared__ float As[32][68];
    __shared__ float Bs[64][65];
    int tid = threadIdx.x;
    int tx = tid & 15, ty = tid >> 4;
    int r0 = blockIdx.y * 32, n0 = blockIdx.x * 64;
    float acc[2][4] = {};
    for (int k0 = 0; k0 < 256; k0 += 64) {
        __syncthreads();
#pragma unroll
        for (int it = 0; it < 2; it++) {
            int idx = it * 256 + tid;
            int i = idx >> 4, k4 = (idx & 15) << 2;
            *(float4*)&As[i][k4] = *(const float4*)&fw[(r0 + i) * 256 + k0 + k4];
        }
#pragma unroll
        for (int it = 0; it < 4; it++) {
            int idx = it * 256 + tid;
            int n = idx >> 4, k4 = (idx & 15) << 2;
            int nn = n0 + n;
            float4 v = {0.f, 0.f, 0.f, 0.f};
            if (nn < O_) v = *(const float4*)&lw[(size_t)nn * 256 + k0 + k4];
            Bs[k4][n] = v.x; Bs[k4 + 1][n] = v.y; Bs[k4 + 2][n] = v.z; Bs[k4 + 3][n] = v.w;
        }
        __syncthreads();
#pragma unroll
        for (int k = 0; k < 64; k++) {
            float a0 = As[ty * 2][k], a1 = As[ty * 2 + 1][k];
            float b0 = Bs[k][tx * 4], b1 = Bs[k][tx * 4 + 1];
            float b2 = Bs[k][tx * 4 + 2], b3 = Bs[k][tx * 4 + 3];
            acc[0][0] += a0 * b0; acc[0][1] += a0 * b1; acc[0][2] += a0 * b2; acc[0][3] += a0 * b3;
            acc[1][0] += a1 * b0; acc[1][1] += a1 * b1; acc[1][2] += a1 * b2; acc[1][3] += a1 * b3;
        }
    }
#pragma unroll
    for (int i = 0; i < 2; i++)
#pragma unroll
        for (int j = 0; j < 4; j++) {
            int n = n0 + tx * 4 + j;
            if (n < O_) out[(size_t)(r0 + ty * 2 + i) * O_ + n] = acc[i][j] + lb[n];
        }
}

extern "C" void kernel_launch(void* const* d_in, const int* in_sizes, int n_in,
                              void* d_out, int out_size, void* d_ws, size_t ws_size,
                              hipStream_t stream) {
    const int* tok = (const int*)d_in[0];
    const float* emb = (const float*)d_in[1];
    const float* Wb = (const float*)d_in[2];
    const float* lw = (const float*)d_in[3];
    const float* lb = (const float*)d_in[4];
    float* out = (float*)d_out;

    char* ws = (char*)d_ws;
    unsigned short* Wbf = (unsigned short*)(ws);            // 131,072 B
    float*          fwp = (float*)(ws + 131072);            // 524,288 B

    hipLaunchKernelGGL(k_wt,   dim3(256),    dim3(256),  0, stream, Wb, Wbf);
    hipLaunchKernelGGL(k_attn, dim3(512),    dim3(1024), 0, stream, tok, emb, Wbf, fwp);
    hipLaunchKernelGGL(k_out,  dim3(16, 16), dim3(256),  0, stream, fwp, lw, lb, out);
}

// Round 14
// 79.216 us; speedup vs baseline: 1.1254x; 1.0258x over previous
//
#include <hip/hip_runtime.h>
#include <hip/hip_bf16.h>
#include <math.h>

// Problem constants
#define B_ 512
#define L_ 256
#define D_ 256
#define V_ 100000
#define O_ 1000

typedef __attribute__((ext_vector_type(8))) short short8;
typedef __attribute__((ext_vector_type(4))) float f32x4;

static __device__ __forceinline__ unsigned short f2bf(float f) {
    union { float f; unsigned u; } v; v.f = f;
    unsigned r = v.u + 0x7FFFu + ((v.u >> 16) & 1u);   // RNE (inputs are finite)
    return (unsigned short)(r >> 16);
}
static __device__ __forceinline__ float bf2f(unsigned short u) {
    union { unsigned u; float f; } v; v.u = ((unsigned)u) << 16;
    return v.f;
}
static __device__ __forceinline__ short8 pack8(float4 a, float4 c) {
    short8 o;
    o[0] = (short)f2bf(a.x); o[1] = (short)f2bf(a.y);
    o[2] = (short)f2bf(a.z); o[3] = (short)f2bf(a.w);
    o[4] = (short)f2bf(c.x); o[5] = (short)f2bf(c.y);
    o[6] = (short)f2bf(c.z); o[7] = (short)f2bf(c.w);
    return o;
}
// fred bank-spread swizzle (valid as fsw(base)+j, j<4, base%4==0)
static __device__ __forceinline__ int fsw(int d) { return d ^ (((d >> 5) & 7) << 2); }

// ---------------- Kernel 1: W_b cast to bf16 (row-major) ----------------
__global__ __launch_bounds__(256) void k_wt(const float* __restrict__ Wb,
                                            unsigned short* __restrict__ Wbf) {
    int i = blockIdx.x * 256 + threadIdx.x;       // 65536
    Wbf[i] = f2bf(Wb[i]);
}

// ---------------- Kernel 2 (fused): per-batch gather + G = E_b*W_b*E_b^T + softmax + f_w ----
// One block per batch, 512 threads (8 waves), 1 block/CU (160KB LDS).
// I=4 ROLE SPLIT (the LDS-BW fix): B-frag bytes/MFMA halve vs 32-row tiles.
//   waves 0-3 (producers): 64 Wb rows in afr[8][4] (128 VGPR). Step s: P1(s):
//     H'[own 64 i][strip s (32 cols)] -> Ht[s&1] (16KB, transposed+swizzled).
//   waves 4-7 (consumers): 64 G rows in afr[8][4] (loaded step 0 from Es).
//     Step s>=1: P2(s-1): G[own 64 l][strip s-1] from Ht[(s-1)&1]; running rowmax.
//     Step 0: waves 5-7 gather THEIR OWN 64 efr-rows (intra-wave LDS visibility ->
//     efr loadable same step); strips reach P1 >=2 barriers before use.
//   Uniform barrier per step (no divergent barriers); one shared afr array
//   (disjoint role phases) so regalloc never sums wfr+efr (r10 lesson).
// Es swizzle: row r, 16B-chunk c at r*512 + (c*16 ^ ((r&7)<<4)).
// tanh(max)=max(tanh) -> softmax over L -> f_w = a^T E (from Es; fred bank-swizzled).
__global__ __launch_bounds__(512) void k_attn(const int* __restrict__ tok,
                                              const float* __restrict__ emb,
                                              const unsigned short* __restrict__ Wbf,
                                              float* __restrict__ fw) {
    __shared__ __align__(16) char lds[163840];
    char* EsC = lds;                                   // 128KB: swizzled E_b
    float* red2    = (float*)(lds + 131072);           // overlay on Ht0 (post-loop): 256 f32
    float* scratch = (float*)(lds + 132096);           // overlay: 16 f32
    float* fred    = (float*)(lds + 132160);           // overlay: 16 x 256 f32

    int b = blockIdx.x;
    int tid = threadIdx.x;
    int wid = tid >> 6, ln = tid & 63;
    int l16 = ln & 15, gp = ln >> 4;
    bool prod = (wid < 4);
    int i0 = (prod ? wid : (wid - 4)) * 64;   // producer: Wb-row block; consumer: G-row block
    const int* tb = tok + (b << 8);

    // ---- prologue: all 512 threads gather rows 0..63 ----
#pragma unroll
    for (int it = 0; it < 4; it++) {
        int c = it * 512 + tid;
        int row = c >> 5, c16 = c & 31;
        const float4* src = (const float4*)(emb + ((size_t)tb[row] << 8) + (c16 << 3));
        short8 o = pack8(src[0], src[1]);
        *(short8*)(EsC + ((row << 9) | ((c16 << 4) ^ ((row & 7) << 4)))) = o;
    }
    __syncthreads();   // barrier 1: rows 0-63 visible

    // afr: producers = 64 Wb rows; consumers = 64 E rows (loaded in step 0)
    short8 afr[8][4];
    if (prod) {
#pragma unroll
        for (int k = 0; k < 8; k++)
#pragma unroll
            for (int rf = 0; rf < 4; rf++)
                afr[k][rf] = *(const short8*)(Wbf + ((i0 + rf * 16 + l16) << 8) + k * 32 + gp * 8);
    }

    float rmax[16];
#pragma unroll
    for (int i = 0; i < 16; i++) rmax[i] = -1e30f;

    // ---- P2 body (consumers): G[own 64 l][32 cols] from HtR ----
    auto P2body = [&](char* HtR) {
        f32x4 acc[4][2] = {};
#pragma unroll
        for (int k0 = 0; k0 < 256; k0 += 32) {
            int kk2 = (k0 + gp * 8) * 2;
            short8 b2[2];
#pragma unroll
            for (int cf = 0; cf < 2; cf++) {
                int m = cf * 16 + l16;
                b2[cf] = *(const short8*)(HtR + ((m << 9) | (kk2 ^ ((m & 7) << 4))));
            }
            int ks = k0 >> 5;
            __builtin_amdgcn_s_setprio(1);
#pragma unroll
            for (int rf = 0; rf < 4; rf++)
#pragma unroll
                for (int cf = 0; cf < 2; cf++)
                    acc[rf][cf] = __builtin_amdgcn_mfma_f32_16x16x32_bf16(
                        afr[ks][rf], b2[cf], acc[rf][cf], 0, 0, 0);
            __builtin_amdgcn_s_setprio(0);
        }
#pragma unroll
        for (int rf = 0; rf < 4; rf++)
#pragma unroll
            for (int r = 0; r < 4; r++)
                rmax[rf * 4 + r] = fmaxf(rmax[rf * 4 + r],
                                         fmaxf(acc[rf][0][r], acc[rf][1][r]));
    };

    // ---- main loop: uniform barrier per step ----
    for (int s = 0; s < 8; s++) {
        if (prod) {
            // P1(s): H'[own 64 i][strip s] -> Ht[s&1]
            char* HtW = lds + 131072 + ((s & 1) << 14);
            f32x4 acc[4][2] = {};
#pragma unroll
            for (int k0 = 0; k0 < 256; k0 += 32) {
                int kk2 = (k0 + gp * 8) * 2;
                short8 b1[2];
#pragma unroll
                for (int cf = 0; cf < 2; cf++) {
                    int jg = s * 32 + cf * 16 + l16;
                    b1[cf] = *(const short8*)(EsC + ((jg << 9) | (kk2 ^ ((jg & 7) << 4))));
                }
                int ks = k0 >> 5;
                __builtin_amdgcn_s_setprio(1);
#pragma unroll
                for (int rf = 0; rf < 4; rf++)
#pragma unroll
                    for (int cf = 0; cf < 2; cf++)
                        acc[rf][cf] = __builtin_amdgcn_mfma_f32_16x16x32_bf16(
                            afr[ks][rf], b1[cf], acc[rf][cf], 0, 0, 0);
                __builtin_amdgcn_s_setprio(0);
            }
#pragma unroll
            for (int rf = 0; rf < 4; rf++)
#pragma unroll
                for (int cf = 0; cf < 2; cf++) {
                    int i = i0 + rf * 16 + gp * 4;
                    int jl = cf * 16 + l16;
                    unsigned long long pk;
                    unsigned short* p = (unsigned short*)&pk;
                    p[0] = f2bf(acc[rf][cf][0]);
                    p[1] = f2bf(acc[rf][cf][1]);
                    p[2] = f2bf(acc[rf][cf][2]);
                    p[3] = f2bf(acc[rf][cf][3]);
                    *(unsigned long long*)(HtW + ((jl << 9) | ((i * 2) ^ ((jl & 7) << 4)))) = pk;
                }
        } else {
            if (s == 0) {
                // waves 5-7: gather own 64 efr-rows (rows i0..i0+64; wave4's rows 0-63 done)
                if (wid > 4) {
#pragma unroll 4
                    for (int it = 0; it < 32; it++) {
                        int ch = it * 64 + ln;
                        int rl = ch >> 5, c16 = ch & 31;
                        int row = i0 + rl;
                        const float4* src = (const float4*)(emb + ((size_t)tb[row] << 8) + (c16 << 3));
                        short8 o = pack8(src[0], src[1]);
                        *(short8*)(EsC + ((row << 9) | ((c16 << 4) ^ ((row & 7) << 4)))) = o;
                    }
                }
                // load efr from own region (same-wave LDS RAW; compiler inserts lgkmcnt)
#pragma unroll
                for (int k = 0; k < 8; k++)
#pragma unroll
                    for (int rf = 0; rf < 4; rf++) {
                        int l = i0 + rf * 16 + l16;
                        afr[k][rf] = *(const short8*)(EsC +
                            ((l << 9) | ((k * 64 + gp * 16) ^ ((l & 7) << 4))));
                    }
            } else {
                P2body(lds + 131072 + (((s - 1) & 1) << 14));
            }
        }
        __syncthreads();
    }

    // ---- consumers: P2(7) from Ht1, then publish rowmax ----
    if (!prod) {
        P2body(lds + 131072 + (1 << 14));
#pragma unroll
        for (int i = 0; i < 16; i++) {
            float v = rmax[i];
            v = fmaxf(v, __shfl_xor(v, 1));
            v = fmaxf(v, __shfl_xor(v, 2));
            v = fmaxf(v, __shfl_xor(v, 4));
            v = fmaxf(v, __shfl_xor(v, 8));
            rmax[i] = v;
        }
        if (l16 == 0) {
#pragma unroll
            for (int rf = 0; rf < 4; rf++)
#pragma unroll
                for (int r = 0; r < 4; r++)
                    red2[i0 + rf * 16 + gp * 4 + r] = rmax[rf * 4 + r];
        }
    }
    __syncthreads();

    // ---- tanh + softmax over the 256 row-maxima ----
    float x = -1e30f;
    if (tid < 256) x = tanhf(red2[tid]);
    float mx = x;
#pragma unroll
    for (int s = 1; s < 64; s <<= 1) mx = fmaxf(mx, __shfl_xor(mx, s));
    if (ln == 0) scratch[wid] = mx;
    __syncthreads();
    float bm = scratch[0];
#pragma unroll
    for (int i = 1; i < 8; i++) bm = fmaxf(bm, scratch[i]);
    float e = (tid < 256) ? expf(x - bm) : 0.f;
    float sm = e;
#pragma unroll
    for (int s = 1; s < 64; s <<= 1) sm += __shfl_xor(sm, s);
    if (ln == 0) scratch[8 + wid] = sm;
    __syncthreads();
    float tot = 0.f;
#pragma unroll
    for (int i = 0; i < 8; i++) tot += scratch[8 + i];
    if (tid < 256) red2[tid] = e / tot;    // aq
    __syncthreads();

    // ---- f_w[d] = sum_l aq[l] * E_b[l][d]  (E from LDS, partials in fred, bank-swizzled) ----
    {
        int g = tid >> 5;                    // 0..15 -> l-range [16g, 16g+16)
        int d0 = (tid & 31) << 3;            // 8 d's per thread
        float s0[8] = {0.f, 0.f, 0.f, 0.f, 0.f, 0.f, 0.f, 0.f};
        int lbase = g << 4;
#pragma unroll
        for (int li = 0; li < 16; li++) {
            int l = lbase + li;
            float aql = red2[l];
            int byt = (l << 9) | ((d0 * 2) ^ ((l & 7) << 4));
            short8 v = *(const short8*)(EsC + byt);
#pragma unroll
            for (int jj = 0; jj < 8; jj++)
                s0[jj] += aql * bf2f((unsigned short)v[jj]);
        }
        f32x4 w0, w1;
        w0[0] = s0[0]; w0[1] = s0[1]; w0[2] = s0[2]; w0[3] = s0[3];
        w1[0] = s0[4]; w1[1] = s0[5]; w1[2] = s0[6]; w1[3] = s0[7];
        *(f32x4*)(fred + g * 256 + fsw(d0)) = w0;
        *(f32x4*)(fred + g * 256 + fsw(d0 + 4)) = w1;
    }
    __syncthreads();
    if (tid < 256) {
        float f = 0.f;
        int dw = fsw(tid);
#pragma unroll
        for (int g2 = 0; g2 < 16; g2++) f += fred[g2 * 256 + dw];
        fw[(b << 8) + tid] = f;
    }
}

// ---------------- Kernel 3: out = f_w @ lin_w^T + lin_b ----------------
// Single-stage LDS (1 barrier): BsT[k][n] transposed (float4 n-reads), As[m][k].
// Tile 32(M)x64(N), 256 blocks.
__global__ __launch_bounds__(256) void k_out(const float* __restrict__ fw,
                                             const float* __restrict__ lw,
                                             const float* __restrict__ lb,
                                             float* __restrict__ out) {
    __shared__ float BsT[256][68];   // [k][n], 69.6KB
    __shared__ float As[32][260];    // [m][k], 33.3KB (260: 16B-aligned rows)
    int tid = threadIdx.x;
    int tx = tid & 15, ty = tid >> 4;
    int r0 = blockIdx.y * 32, n0 = blockIdx.x * 64;
    // stage As: 32 rows x 64 float4 = 2048 / 256 thr = 8 its
#pragma unroll
    for (int it = 0; it < 8; it++) {
        int f4 = it * 256 + tid;
        int i = f4 >> 6, kc = (f4 & 63) << 2;
        *(float4*)&As[i][kc] = *(const float4*)&fw[(r0 + i) * 256 + kc];
    }
    // stage BsT: 64 n-rows x 64 float4 = 4096 / 256 = 16 its (transposed scalar stores)
#pragma unroll
    for (int it = 0; it < 16; it++) {
        int f4 = it * 256 + tid;
        int n = f4 >> 6, kc = (f4 & 63) << 2;
        int nn = n0 + n;
        float4 v = {0.f, 0.f, 0.f, 0.f};
        if (nn < O_) v = *(const float4*)&lw[(size_t)nn * 256 + kc];
        BsT[kc][n] = v.x; BsT[kc + 1][n] = v.y; BsT[kc + 2][n] = v.z; BsT[kc + 3][n] = v.w;
    }
    __syncthreads();
    float acc[2][4] = {};
#pragma unroll 4
    for (int k = 0; k < 256; k++) {
        float4 bv = *(const float4*)&BsT[k][tx * 4];
        float a0 = As[ty * 2][k], a1 = As[ty * 2 + 1][k];
        acc[0][0] += a0 * bv.x; acc[0][1] += a0 * bv.y; acc[0][2] += a0 * bv.z; acc[0][3] += a0 * bv.w;
        acc[1][0] += a1 * bv.x; acc[1][1] += a1 * bv.y; acc[1][2] += a1 * bv.z; acc[1][3] += a1 * bv.w;
    }
#pragma unroll
    for (int i = 0; i < 2; i++)
#pragma unroll
        for (int j = 0; j < 4; j++) {
            int n = n0 + tx * 4 + j;
            if (n < O_) out[(size_t)(r0 + ty * 2 + i) * O_ + n] = acc[i][j] + lb[n];
        }
}

extern "C" void kernel_launch(void* const* d_in, const int* in_sizes, int n_in,
                              void* d_out, int out_size, void* d_ws, size_t ws_size,
                              hipStream_t stream) {
    const int* tok = (const int*)d_in[0];
    const float* emb = (const float*)d_in[1];
    const float* Wb = (const float*)d_in[2];
    const float* lw = (const float*)d_in[3];
    const float* lb = (const float*)d_in[4];
    float* out = (float*)d_out;

    char* ws = (char*)d_ws;
    unsigned short* Wbf = (unsigned short*)(ws);            // 131,072 B
    float*          fwp = (float*)(ws + 131072);            // 524,288 B

    hipLaunchKernelGGL(k_wt,   dim3(256),    dim3(256), 0, stream, Wb, Wbf);
    hipLaunchKernelGGL(k_attn, dim3(512),    dim3(512), 0, stream, tok, emb, Wbf, fwp);
    hipLaunchKernelGGL(k_out,  dim3(16, 16), dim3(256), 0, stream, fwp, lw, lb, out);
}